// Round 1
// baseline (571.795 us; speedup 1.0000x reference)
//
#include <hip/hip_runtime.h>
#include <math.h>

#define B 32
#define C 1536
#define T 2000
#define NBT (B * T)        // 64000
#define CSPLIT 8
#define CCH (C / CSPLIT)   // 192
#define T4 (T / 4)         // 500
#define BN_EPS 1e-5f
#define K2_BLOCKS 250      // 250 * 256 == 64000 exactly

// -------- ws layout (floats) --------
// a_part : [CSPLIT][NBT]            (512000)
// a      : [NBT]                    (64000)
// attn   : [NBT]                    (64000)
// psums  : [2 * K2_BLOCKS]          (500)
// total ~2.56 MB

// Kernel 1: partial 1x1 conv over a c-chunk. Each thread owns 4 consecutive t
// (float4). Fully-coalesced 1KB/wave loads; c-loop unrolled for MLP.
__global__ __launch_bounds__(256) void k1_conv(const float* __restrict__ x,
                                               const float* __restrict__ w,
                                               float* __restrict__ a_part) {
  const int t4 = blockIdx.x * 256 + threadIdx.x;   // float4 index in [0,500)
  const int b  = blockIdx.y;
  const int ck = blockIdx.z;
  if (t4 >= T4) return;
  const int c0 = ck * CCH;
  const float4* xp = reinterpret_cast<const float4*>(x) + ((size_t)b * C + c0) * T4;
  float4 acc = make_float4(0.f, 0.f, 0.f, 0.f);
#pragma unroll 8
  for (int j = 0; j < CCH; ++j) {
    const float wc = w[c0 + j];            // wave-uniform -> scalar load
    const float4 v = xp[(size_t)j * T4 + t4];
    acc.x += v.x * wc; acc.y += v.y * wc; acc.z += v.z * wc; acc.w += v.w * wc;
  }
  reinterpret_cast<float4*>(a_part + (size_t)ck * NBT + b * T)[t4] = acc;
}

// Kernel 2: a[b,t] = sum of partials + conv_b; per-block tree-reduced
// sum / sumsq for the global BatchNorm stats (deterministic, no atomics).
__global__ __launch_bounds__(256) void k2_reduce(const float* __restrict__ a_part,
                                                 const float* __restrict__ conv_b,
                                                 float* __restrict__ a,
                                                 float* __restrict__ psums) {
  const int i = blockIdx.x * 256 + threadIdx.x;    // < 64000 exactly
  float v = conv_b[0];
#pragma unroll
  for (int k = 0; k < CSPLIT; ++k) v += a_part[(size_t)k * NBT + i];
  a[i] = v;

  float s1 = v, s2 = v * v;
#pragma unroll
  for (int off = 32; off; off >>= 1) {
    s1 += __shfl_xor(s1, off);
    s2 += __shfl_xor(s2, off);
  }
  __shared__ float ls1[4], ls2[4];
  const int wid = threadIdx.x >> 6, lane = threadIdx.x & 63;
  if (lane == 0) { ls1[wid] = s1; ls2[wid] = s2; }
  __syncthreads();
  if (threadIdx.x == 0) {
    psums[blockIdx.x]             = ls1[0] + ls1[1] + ls1[2] + ls1[3];
    psums[K2_BLOCKS + blockIdx.x] = ls2[0] + ls2[1] + ls2[2] + ls2[3];
  }
}

// Kernel 3: one block per batch row. Redundantly reduce the 250 partial pairs
// -> mu/var, then BN + tanh + softmax over time (row staged in LDS).
__global__ __launch_bounds__(256) void k3_softmax(const float* __restrict__ a,
                                                  const float* __restrict__ psums,
                                                  const float* __restrict__ gamma,
                                                  const float* __restrict__ beta,
                                                  float* __restrict__ attn) {
  __shared__ float sv[T];
  __shared__ float r1[4], r2[4], r3[4], r4[4];
  const int tid = threadIdx.x;
  const int wid = tid >> 6, lane = tid & 63;

  // ---- global BN stats ----
  float s1 = 0.f, s2 = 0.f;
  if (tid < K2_BLOCKS) { s1 = psums[tid]; s2 = psums[K2_BLOCKS + tid]; }
#pragma unroll
  for (int off = 32; off; off >>= 1) {
    s1 += __shfl_xor(s1, off);
    s2 += __shfl_xor(s2, off);
  }
  if (lane == 0) { r1[wid] = s1; r2[wid] = s2; }
  __syncthreads();
  const float tot1 = r1[0] + r1[1] + r1[2] + r1[3];
  const float tot2 = r2[0] + r2[1] + r2[2] + r2[3];
  const float mu  = tot1 / (float)NBT;
  const float var = tot2 / (float)NBT - mu * mu;   // biased var
  const float rs  = 1.0f / sqrtf(var + BN_EPS);
  const float g = gamma[0], be = beta[0];

  // ---- tanh(BN(a)) + row max ----
  const int b = blockIdx.x;
  const float* ab = a + b * T;
  float lmax = -1e30f;
  for (int t = tid; t < T; t += 256) {
    const float v = tanhf((ab[t] - mu) * rs * g + be);
    sv[t] = v;
    lmax = fmaxf(lmax, v);
  }
#pragma unroll
  for (int off = 32; off; off >>= 1) lmax = fmaxf(lmax, __shfl_xor(lmax, off));
  if (lane == 0) r3[wid] = lmax;
  __syncthreads();
  const float m = fmaxf(fmaxf(r3[0], r3[1]), fmaxf(r3[2], r3[3]));

  // ---- exp + row sum ----
  float lsum = 0.f;
  for (int t = tid; t < T; t += 256) {
    const float p = expf(sv[t] - m);
    sv[t] = p;                 // each thread overwrites only its own slots
    lsum += p;
  }
#pragma unroll
  for (int off = 32; off; off >>= 1) lsum += __shfl_xor(lsum, off);
  if (lane == 0) r4[wid] = lsum;
  __syncthreads();
  const float inv = 1.0f / (r4[0] + r4[1] + r4[2] + r4[3]);

  for (int t = tid; t < T; t += 256) attn[b * T + t] = sv[t] * inv;
}

// Kernel 4: one wave per (b,c) row. mean = sum(x*attn), m2 = sum(x^2*attn),
// std = sqrt(max(m2 - mean^2, 1e-10)). float4 loads; attn row is L2-resident.
__global__ __launch_bounds__(256) void k4_pool(const float* __restrict__ x,
                                               const float* __restrict__ attn,
                                               float* __restrict__ out) {
  const int wid  = threadIdx.x >> 6;
  const int lane = threadIdx.x & 63;
  const int row  = blockIdx.x * 4 + wid;   // b*C + c
  const int b = row / C;
  const int c = row - b * C;
  const float4* xr = reinterpret_cast<const float4*>(x)    + (size_t)row * T4;
  const float4* ar = reinterpret_cast<const float4*>(attn) + (size_t)b   * T4;
  float sxa = 0.f, sx2a = 0.f;
  for (int j = lane; j < T4; j += 64) {
    const float4 xv = xr[j];
    const float4 av = ar[j];
    sxa  += xv.x * av.x + xv.y * av.y + xv.z * av.z + xv.w * av.w;
    sx2a += xv.x * xv.x * av.x + xv.y * xv.y * av.y +
            xv.z * xv.z * av.z + xv.w * xv.w * av.w;
  }
#pragma unroll
  for (int off = 32; off; off >>= 1) {
    sxa  += __shfl_xor(sxa, off);
    sx2a += __shfl_xor(sx2a, off);
  }
  if (lane == 0) {
    const float mean = sxa;
    out[(size_t)b * 2 * C + c]     = mean;
    out[(size_t)b * 2 * C + C + c] = sqrtf(fmaxf(sx2a - mean * mean, 1e-10f));
  }
}

extern "C" void kernel_launch(void* const* d_in, const int* in_sizes, int n_in,
                              void* d_out, int out_size, void* d_ws, size_t ws_size,
                              hipStream_t stream) {
  const float* x      = (const float*)d_in[0];
  const float* conv_w = (const float*)d_in[1];
  const float* conv_b = (const float*)d_in[2];
  const float* gamma  = (const float*)d_in[3];
  const float* beta   = (const float*)d_in[4];
  float* out = (float*)d_out;

  float* ws     = (float*)d_ws;
  float* a_part = ws;                                  // CSPLIT*NBT
  float* a      = a_part + (size_t)CSPLIT * NBT;       // NBT
  float* attn   = a + NBT;                             // NBT
  float* psums  = attn + NBT;                          // 2*K2_BLOCKS

  dim3 g1((T4 + 255) / 256, B, CSPLIT);                // (2, 32, 8)
  k1_conv<<<g1, 256, 0, stream>>>(x, conv_w, a_part);
  k2_reduce<<<K2_BLOCKS, 256, 0, stream>>>(a_part, conv_b, a, psums);
  k3_softmax<<<B, 256, 0, stream>>>(a, psums, gamma, beta, attn);
  k4_pool<<<(B * C) / 4, 256, 0, stream>>>(x, attn, out);
}

// Round 2
// 561.334 us; speedup vs baseline: 1.0186x; 1.0186x over previous
//
#include <hip/hip_runtime.h>
#include <math.h>

#define B 32
#define C 1536
#define T 2000
#define NBT (B * T)        // 64000
#define CSPLIT 16
#define CCH (C / CSPLIT)   // 96
#define T4 (T / 4)         // 500
#define BN_EPS 1e-5f
#define K2_BLOCKS 250      // 250 * 256 == 64000 exactly

using f4 = __attribute__((ext_vector_type(4))) float;

// -------- ws layout (floats) --------
// a_part : [CSPLIT][NBT]   (1,024,000)
// a      : [NBT]           (64,000)
// attn   : [NBT]           (64,000)
// psums  : [2*K2_BLOCKS]   (500)

// Kernel 1: partial 1x1 conv over a 96-channel chunk. 1024 blocks (4/CU,
// 16 waves/CU). Thread owns one float4 t-column; 96 strided row loads,
// coalesced 1KB/wave; 8-deep unroll keeps 8 loads in flight per lane.
__global__ __launch_bounds__(256) void k1_conv(const float* __restrict__ x,
                                               const float* __restrict__ w,
                                               float* __restrict__ a_part) {
  const int t4 = blockIdx.x * 256 + threadIdx.x;   // float4 index in [0,500)
  const int b  = blockIdx.y;
  const int ck = blockIdx.z;
  if (t4 >= T4) return;
  const int c0 = ck * CCH;
  const f4* xp = reinterpret_cast<const f4*>(x) + ((size_t)b * C + c0) * T4;
  f4 acc = (f4)0.f;
#pragma unroll 8
  for (int j = 0; j < CCH; ++j) {
    const float wc = w[c0 + j];            // wave-uniform -> scalar load
    const f4 v = xp[(size_t)j * T4 + t4];
    acc += v * wc;
  }
  reinterpret_cast<f4*>(a_part + (size_t)ck * NBT + b * T)[t4] = acc;
}

// Kernel 2: a[b,t] = sum of 16 partials + conv_b; block tree-reduce of
// sum / sumsq -> 250 partial pairs (deterministic, no atomics).
__global__ __launch_bounds__(256) void k2_reduce(const float* __restrict__ a_part,
                                                 const float* __restrict__ conv_b,
                                                 float* __restrict__ a,
                                                 float* __restrict__ psums) {
  const int i = blockIdx.x * 256 + threadIdx.x;    // < 64000 exactly
  float v = conv_b[0];
#pragma unroll
  for (int k = 0; k < CSPLIT; ++k) v += a_part[(size_t)k * NBT + i];
  a[i] = v;

  float s1 = v, s2 = v * v;
#pragma unroll
  for (int off = 32; off; off >>= 1) {
    s1 += __shfl_xor(s1, off);
    s2 += __shfl_xor(s2, off);
  }
  __shared__ float ls1[4], ls2[4];
  const int wid = threadIdx.x >> 6, lane = threadIdx.x & 63;
  if (lane == 0) { ls1[wid] = s1; ls2[wid] = s2; }
  __syncthreads();
  if (threadIdx.x == 0) {
    psums[blockIdx.x]             = ls1[0] + ls1[1] + ls1[2] + ls1[3];
    psums[K2_BLOCKS + blockIdx.x] = ls2[0] + ls2[1] + ls2[2] + ls2[3];
  }
}

// Kernel 3: one block per batch row (512 thr). Redundantly reduce the 250
// partial pairs -> mu/var, then BN + tanh + softmax over time in LDS.
__global__ __launch_bounds__(512) void k3_softmax(const float* __restrict__ a,
                                                  const float* __restrict__ psums,
                                                  const float* __restrict__ gamma,
                                                  const float* __restrict__ beta,
                                                  float* __restrict__ attn) {
  __shared__ float sv[T];
  __shared__ float r1[8], r2[8], r3[8], r4[8];
  const int tid = threadIdx.x;
  const int wid = tid >> 6, lane = tid & 63;

  // ---- global BN stats ----
  float s1 = 0.f, s2 = 0.f;
  if (tid < K2_BLOCKS) { s1 = psums[tid]; s2 = psums[K2_BLOCKS + tid]; }
#pragma unroll
  for (int off = 32; off; off >>= 1) {
    s1 += __shfl_xor(s1, off);
    s2 += __shfl_xor(s2, off);
  }
  if (lane == 0) { r1[wid] = s1; r2[wid] = s2; }
  __syncthreads();
  float tot1 = 0.f, tot2 = 0.f;
#pragma unroll
  for (int k = 0; k < 8; ++k) { tot1 += r1[k]; tot2 += r2[k]; }
  const float mu  = tot1 / (float)NBT;
  const float var = tot2 / (float)NBT - mu * mu;   // biased var
  const float rs  = 1.0f / sqrtf(var + BN_EPS);
  const float g = gamma[0], be = beta[0];

  // ---- tanh(BN(a)) + row max ----
  const int b = blockIdx.x;
  const float* ab = a + b * T;
  float lmax = -1e30f;
  for (int t = tid; t < T; t += 512) {
    const float v = tanhf((ab[t] - mu) * rs * g + be);
    sv[t] = v;
    lmax = fmaxf(lmax, v);
  }
#pragma unroll
  for (int off = 32; off; off >>= 1) lmax = fmaxf(lmax, __shfl_xor(lmax, off));
  if (lane == 0) r3[wid] = lmax;
  __syncthreads();
  float m = -1e30f;
#pragma unroll
  for (int k = 0; k < 8; ++k) m = fmaxf(m, r3[k]);

  // ---- exp + row sum ----
  float lsum = 0.f;
  for (int t = tid; t < T; t += 512) {
    const float p = expf(sv[t] - m);
    sv[t] = p;
    lsum += p;
  }
#pragma unroll
  for (int off = 32; off; off >>= 1) lsum += __shfl_xor(lsum, off);
  if (lane == 0) r4[wid] = lsum;
  __syncthreads();
  float tot = 0.f;
#pragma unroll
  for (int k = 0; k < 8; ++k) tot += r4[k];
  const float inv = 1.0f / tot;

  for (int t = tid; t < T; t += 512) attn[b * T + t] = sv[t] * inv;
}

// Kernel 4: one wave per (b,c) row. Fully unrolled: 7 full rounds + 1 tail
// (lane<52), all 16 loads issued before the FMA reduce. x reads are
// nontemporal (last use -> don't evict attn / L3-resident x tail).
__global__ __launch_bounds__(256) void k4_pool(const float* __restrict__ x,
                                               const float* __restrict__ attn,
                                               float* __restrict__ out) {
  const int wid  = threadIdx.x >> 6;
  const int lane = threadIdx.x & 63;
  const int row  = blockIdx.x * 4 + wid;   // b*C + c
  const int b = row / C;
  const int c = row - b * C;
  const f4* xr = reinterpret_cast<const f4*>(x)    + (size_t)row * T4;
  const f4* ar = reinterpret_cast<const f4*>(attn) + (size_t)b   * T4;

  f4 xv[8], av[8];
#pragma unroll
  for (int j = 0; j < 7; ++j) {
    xv[j] = __builtin_nontemporal_load(xr + j * 64 + lane);
    av[j] = ar[j * 64 + lane];
  }
  if (lane < 52) {   // 500 = 7*64 + 52
    xv[7] = __builtin_nontemporal_load(xr + 448 + lane);
    av[7] = ar[448 + lane];
  } else {
    xv[7] = (f4)0.f;
    av[7] = (f4)0.f;
  }

  float sxa = 0.f, sx2a = 0.f;
#pragma unroll
  for (int j = 0; j < 8; ++j) {
    const f4 xa = xv[j] * av[j];
    sxa  += xa.x + xa.y + xa.z + xa.w;
    const f4 x2a = xv[j] * xa;
    sx2a += x2a.x + x2a.y + x2a.z + x2a.w;
  }
#pragma unroll
  for (int off = 32; off; off >>= 1) {
    sxa  += __shfl_xor(sxa, off);
    sx2a += __shfl_xor(sx2a, off);
  }
  if (lane == 0) {
    const float mean = sxa;
    out[(size_t)b * 2 * C + c]     = mean;
    out[(size_t)b * 2 * C + C + c] = sqrtf(fmaxf(sx2a - mean * mean, 1e-10f));
  }
}

extern "C" void kernel_launch(void* const* d_in, const int* in_sizes, int n_in,
                              void* d_out, int out_size, void* d_ws, size_t ws_size,
                              hipStream_t stream) {
  const float* x      = (const float*)d_in[0];
  const float* conv_w = (const float*)d_in[1];
  const float* conv_b = (const float*)d_in[2];
  const float* gamma  = (const float*)d_in[3];
  const float* beta   = (const float*)d_in[4];
  float* out = (float*)d_out;

  float* ws     = (float*)d_ws;
  float* a_part = ws;                                  // CSPLIT*NBT
  float* a      = a_part + (size_t)CSPLIT * NBT;       // NBT
  float* attn   = a + NBT;                             // NBT
  float* psums  = attn + NBT;                          // 2*K2_BLOCKS

  dim3 g1((T4 + 255) / 256, B, CSPLIT);                // (2, 32, 16)
  k1_conv<<<g1, 256, 0, stream>>>(x, conv_w, a_part);
  k2_reduce<<<K2_BLOCKS, 256, 0, stream>>>(a_part, conv_b, a, psums);
  k3_softmax<<<B, 512, 0, stream>>>(a, psums, gamma, beta, attn);
  k4_pool<<<(B * C) / 4, 256, 0, stream>>>(x, attn, out);
}